// Round 9
// baseline (230.604 us; speedup 1.0000x reference)
//
#include <hip/hip_runtime.h>

#define BATCH 8
#define NNODE 10000
#define NEDGE 320000
#define HD    128
#define NROW  (BATCH * NNODE)       // 80000 rows
#define NEDG_TOT (BATCH * NEDGE)    // 2.56M edges
#define SCAN_B ((NROW + 255) / 256) // 313
#define LDW 136                     // padded LDS row stride (bf16)
#define KB  64                      // hist/scatter blocks per batch
#define CEB (NEDGE / KB)            // 5000 edges per block
#define G   64                      // rows per coarse bucket
#define NBUCK 157                   // ceil(NNODE/G)
#define NBP 160                     // padded bucket stride
#define NBT (BATCH * NBP)           // 1280

typedef __attribute__((ext_vector_type(8))) short short8;
typedef __attribute__((ext_vector_type(4))) float f32x4;

__device__ __forceinline__ short f2bf(float f) {
    unsigned u = __float_as_uint(f);
    unsigned r = u + 0x7FFFu + ((u >> 16) & 1u);   // RNE
    return (short)(r >> 16);
}
__device__ __forceinline__ float bflo(unsigned y) { return __uint_as_float(y << 16); }
__device__ __forceinline__ float bfhi(unsigned y) { return __uint_as_float(y & 0xffff0000u); }

// ---------- pass 1: per-block LDS histograms (fine cnt + deg); coarse cnt from scnt ----------
__global__ __launch_bounds__(256) void k_hist(const float* __restrict__ adj,
                                              const int* __restrict__ src,
                                              float* __restrict__ bdeg,
                                              int* __restrict__ bcnt,
                                              int* __restrict__ cc) {
    __shared__ float sdeg[NNODE];   // 40 KB
    __shared__ int   scnt[NNODE];   // 40 KB
    int t = threadIdx.x, blk = blockIdx.x;
    for (int i = t; i < NNODE; i += 256) { sdeg[i] = 0.f; scnt[i] = 0; }
    __syncthreads();
    int b = blk >> 6, kb = blk & (KB - 1);
    long e0 = (long)b * NEDGE + (long)kb * CEB;
    for (int i = t; i < CEB; i += 256) {
        long e = e0 + i;
        int s = src[e];
        atomicAdd(&sdeg[s], adj[e]);
        atomicAdd(&scnt[s], 1);
    }
    __syncthreads();
    float* bd = bdeg + (long)blk * NNODE;
    int*   bc = bcnt + (long)blk * NNODE;
    for (int i = t; i < NNODE; i += 256) { bd[i] = sdeg[i]; bc[i] = scnt[i]; }
    // coarse per-block bucket counts (buckets of 64 rows) from scnt
    for (int t0 = t; t0 < NBP; t0 += 256) {
        int s = 0, base = t0 * G;
        #pragma unroll
        for (int j = 0; j < G; ++j) {
            int node = base + j;
            if (node < NNODE) s += scnt[node];
        }
        cc[blk * NBP + t0] = s;
    }
}

// ---------- row totals + norm ----------
__global__ __launch_bounds__(256) void k_sum(const int* __restrict__ bcnt,
                                             const float* __restrict__ bdeg,
                                             int* __restrict__ total,
                                             float* __restrict__ norm) {
    int r = blockIdx.x * 256 + threadIdx.x;
    if (r >= NROW) return;
    int b = r / NNODE, n = r % NNODE;
    const int*   bc = bcnt + (long)b * KB * NNODE + n;
    const float* bd = bdeg + (long)b * KB * NNODE + n;
    int s = 0; float ds = 0.f;
    #pragma unroll
    for (int k = 0; k < KB; ++k) {
        s  += bc[(long)k * NNODE];
        ds += bd[(long)k * NNODE];
    }
    total[r] = s;
    norm[r] = rsqrtf(ds + 1e-6f);
}

// ---------- fine scan over PADDED counts (even -> 16B-aligned buckets) ----------
__global__ __launch_bounds__(256) void k_scan1(const int* __restrict__ total,
                                               int* __restrict__ incl,
                                               int* __restrict__ bsum) {
    __shared__ int s[256];
    int t = threadIdx.x, g = blockIdx.x * 256 + t;
    int v = (g < NROW) ? ((total[g] + 1) & ~1) : 0;
    s[t] = v; __syncthreads();
    for (int off = 1; off < 256; off <<= 1) {
        int a = s[t]; int add = (t >= off) ? s[t - off] : 0;
        __syncthreads();
        s[t] = a + add;
        __syncthreads();
    }
    if (g < NROW) incl[g] = s[t];
    if (t == 255) bsum[blockIdx.x] = s[255];
}
__global__ __launch_bounds__(512) void k_scan2(const int* __restrict__ bsum,
                                               int* __restrict__ boffs) {
    __shared__ int s[512];
    int t = threadIdx.x;
    int v = (t < SCAN_B) ? bsum[t] : 0;
    s[t] = v; __syncthreads();
    for (int off = 1; off < 512; off <<= 1) {
        int a = s[t]; int add = (t >= off) ? s[t - off] : 0;
        __syncthreads();
        s[t] = a + add;
        __syncthreads();
    }
    if (t < SCAN_B) boffs[t] = s[t] - v;
}
__global__ __launch_bounds__(256) void k_fix(const int* __restrict__ total,
                                             const int* __restrict__ boffs,
                                             int* __restrict__ rowptr) {
    int g = blockIdx.x * 256 + threadIdx.x;
    if (g >= NROW) return;
    int pt = (total[g] + 1) & ~1;
    rowptr[g] = rowptr[g] - pt + boffs[blockIdx.x];   // incl -> excl (even)
}

// ---------- coarse chain merged: totals + scan + per-block bases (1 block) ----------
__global__ __launch_bounds__(256) void k_coarse(int* __restrict__ cc,
                                                int* __restrict__ tot_c,
                                                int* __restrict__ cbase) {
    __shared__ int part[256];
    int t = threadIdx.x;
    int tot[5], loc[5]; int run = 0;
    #pragma unroll
    for (int j = 0; j < 5; ++j) {
        int gi = t * 5 + j, b = gi / NBP, bk = gi % NBP;
        int s = 0;
        for (int k = 0; k < KB; ++k) s += cc[(b * KB + k) * NBP + bk];
        tot[j] = s; loc[j] = run; run += s;
    }
    part[t] = run; __syncthreads();
    for (int off = 1; off < 256; off <<= 1) {
        int a = part[t]; int add = (t >= off) ? part[t - off] : 0;
        __syncthreads();
        part[t] = a + add;
        __syncthreads();
    }
    int excl = (t == 0) ? 0 : part[t - 1];
    #pragma unroll
    for (int j = 0; j < 5; ++j) {
        int gi = t * 5 + j, b = gi / NBP, bk = gi % NBP;
        tot_c[gi] = tot[j];
        cbase[gi] = excl + loc[j];
        int run2 = excl + loc[j];
        for (int k = 0; k < KB; ++k) {
            int idx = (b * KB + k) * NBP + bk;
            int c = cc[idx];
            cc[idx] = run2;
            run2 += c;
        }
    }
}

// ---------- phase A: coarse scatter (64-row buckets), fold norm[dst] into value ----------
__global__ __launch_bounds__(256) void k_scatA(const float* __restrict__ adj,
                                               const int* __restrict__ src,
                                               const int* __restrict__ dst,
                                               const float* __restrict__ norm,
                                               const int* __restrict__ cbases,
                                               int2* __restrict__ epairA) {
    __shared__ int cur[NBP];
    int t = threadIdx.x, blk = blockIdx.x;
    if (t < NBP) cur[t] = cbases[blk * NBP + t];
    __syncthreads();
    int b = blk >> 6, kb = blk & (KB - 1);
    const float* nb = norm + b * NNODE;
    long e0 = (long)b * NEDGE + (long)kb * CEB;
    for (int i = t; i < CEB; i += 256) {
        long e = e0 + i;
        int s = src[e], d = dst[e];
        float v = adj[e] * nb[d];
        int p = atomicAdd(&cur[s >> 6], 1);
        epairA[p] = make_int2((s << 16) | d, __float_as_int(v));
    }
}

// ---------- phase B: refine within bucket (16KB window) to exact row slots ----------
__global__ __launch_bounds__(256) void k_refine(const int* __restrict__ cbase,
                                                const int* __restrict__ tot_c,
                                                const int2* __restrict__ epairA,
                                                const int* __restrict__ rowptr,
                                                int2* __restrict__ epairB) {
    __shared__ int cur[G];
    int t = threadIdx.x;
    int batch = blockIdx.x & 7, bk = blockIdx.x >> 3;
    if (t < G) {
        int node = bk * G + t;
        cur[t] = (node < NNODE) ? rowptr[batch * NNODE + node] : 0;
    }
    __syncthreads();
    int gi = batch * NBP + bk;
    int p0 = cbase[gi], n = tot_c[gi];
    for (int i = t; i < n; i += 256) {
        int2 e = epairA[p0 + i];
        int rl = (e.x >> 16) & (G - 1);
        int p = atomicAdd(&cur[rl], 1);
        epairB[p] = make_int2(e.x & 0xffff, e.y);
    }
}

// ---------- weights -> bf16 transposed ----------
__global__ __launch_bounds__(256) void k_wcvt(const float* __restrict__ th,
                                              const float* __restrict__ Wt,
                                              const float* __restrict__ Wh,
                                              short* __restrict__ wbf) {
    int i = blockIdx.x * 256 + threadIdx.x;
    int w = i >> 14, idx = i & 16383;
    int n = idx >> 7, k = idx & 127;
    const float* W = (w == 0) ? th : ((w == 1) ? Wt : Wh);
    wbf[i] = f2bf(W[k * HD + n]);
}

// ---------- Y = bf16( x@theta )  (unnormalized; norms folded elsewhere) ----------
__global__ __launch_bounds__(256) void k_theta(const float* __restrict__ x,
                                               const short* __restrict__ thT,
                                               short* __restrict__ Y) {
    __shared__ short lb[HD * LDW];
    int tx = threadIdx.x;
    for (int i = tx; i < HD * 16; i += 256) {
        int n = i >> 4, kc = (i & 15) << 3;
        *(float4*)(&lb[n * LDW + kc]) = *(const float4*)(&thT[n * HD + kc]);
    }
    __syncthreads();

    int wv = tx >> 6, l = tx & 63;
    long row0 = (long)blockIdx.x * 64 + wv * 16;
    int mrow = l & 15, kg = l >> 4;
    const float* xp = x + (row0 + mrow) * HD + kg * 8;

    f32x4 acc[8];
    #pragma unroll
    for (int f = 0; f < 8; ++f) acc[f] = (f32x4){0.f, 0.f, 0.f, 0.f};

    #pragma unroll
    for (int c = 0; c < 4; ++c) {
        float4 a0 = *(const float4*)(xp + c * 32);
        float4 a1 = *(const float4*)(xp + c * 32 + 4);
        short8 a;
        a[0]=f2bf(a0.x); a[1]=f2bf(a0.y); a[2]=f2bf(a0.z); a[3]=f2bf(a0.w);
        a[4]=f2bf(a1.x); a[5]=f2bf(a1.y); a[6]=f2bf(a1.z); a[7]=f2bf(a1.w);
        #pragma unroll
        for (int f = 0; f < 8; ++f) {
            short8 b = *(short8*)(&lb[(16 * f + mrow) * LDW + c * 32 + kg * 8]);
            acc[f] = __builtin_amdgcn_mfma_f32_16x16x32_bf16(a, b, acc[f], 0, 0, 0);
        }
    }
    #pragma unroll
    for (int f = 0; f < 8; ++f)
        #pragma unroll
        for (int r = 0; r < 4; ++r)
            Y[(row0 + kg * 4 + r) * HD + 16 * f + mrow] = f2bf(acc[f][r]);
}

// ---------- gather SpMM, XCD-swizzled, software-pipelined metadata ----------
__global__ __launch_bounds__(256) void k_gather(const int* __restrict__ rowptr,
                                                const int* __restrict__ total,
                                                const int2* __restrict__ epair,
                                                const short* __restrict__ Y,
                                                const float* __restrict__ norm,
                                                float* __restrict__ out) {
    int batch = blockIdx.x & 7;
    int ib    = blockIdx.x >> 3;
    int wave = threadIdx.x >> 6, lane = threadIdx.x & 63;
    long r = (long)batch * NNODE + ib * 4 + wave;
    const short* Yb = Y + (long)batch * NNODE * HD + 2 * lane;
    int p0 = __builtin_amdgcn_readfirstlane(rowptr[r]);   // even -> 16B aligned
    int n  = __builtin_amdgcn_readfirstlane(total[r]);
    const int4* ep4 = (const int4*)(epair + p0);
    float ax = 0.f, ay = 0.f;
    int nv = n >> 3;                 // 8-edge groups
    int4 m0, m1, m2, m3;
    if (nv > 0) { m0 = ep4[0]; m1 = ep4[1]; m2 = ep4[2]; m3 = ep4[3]; }
    for (int g = 0; g < nv; ++g) {
        int4 c0 = m0, c1 = m1, c2 = m2, c3 = m3;
        if (g + 1 < nv) {            // prefetch next group's metadata
            int bq = (g + 1) << 2;
            m0 = ep4[bq]; m1 = ep4[bq + 1]; m2 = ep4[bq + 2]; m3 = ep4[bq + 3];
        }
        unsigned y0 = *(const unsigned*)(Yb + (long)c0.x * HD);
        unsigned y1 = *(const unsigned*)(Yb + (long)c0.z * HD);
        unsigned y2 = *(const unsigned*)(Yb + (long)c1.x * HD);
        unsigned y3 = *(const unsigned*)(Yb + (long)c1.z * HD);
        unsigned y4 = *(const unsigned*)(Yb + (long)c2.x * HD);
        unsigned y5 = *(const unsigned*)(Yb + (long)c2.z * HD);
        unsigned y6 = *(const unsigned*)(Yb + (long)c3.x * HD);
        unsigned y7 = *(const unsigned*)(Yb + (long)c3.z * HD);
        float v0 = __int_as_float(c0.y), v1 = __int_as_float(c0.w);
        float v2 = __int_as_float(c1.y), v3 = __int_as_float(c1.w);
        float v4 = __int_as_float(c2.y), v5 = __int_as_float(c2.w);
        float v6 = __int_as_float(c3.y), v7 = __int_as_float(c3.w);
        ax += v0 * bflo(y0); ay += v0 * bfhi(y0);
        ax += v1 * bflo(y1); ay += v1 * bfhi(y1);
        ax += v2 * bflo(y2); ay += v2 * bfhi(y2);
        ax += v3 * bflo(y3); ay += v3 * bfhi(y3);
        ax += v4 * bflo(y4); ay += v4 * bfhi(y4);
        ax += v5 * bflo(y5); ay += v5 * bfhi(y5);
        ax += v6 * bflo(y6); ay += v6 * bfhi(y6);
        ax += v7 * bflo(y7); ay += v7 * bfhi(y7);
    }
    int i = nv << 3;
    for (; i + 2 <= n; i += 2) {
        int4 eA = ep4[i >> 1];
        unsigned y0 = *(const unsigned*)(Yb + (long)eA.x * HD);
        unsigned y1 = *(const unsigned*)(Yb + (long)eA.z * HD);
        float v0 = __int_as_float(eA.y), v1 = __int_as_float(eA.w);
        ax += v0 * bflo(y0); ay += v0 * bfhi(y0);
        ax += v1 * bflo(y1); ay += v1 * bfhi(y1);
    }
    if (i < n) {
        int2 e = epair[p0 + i];
        unsigned y = *(const unsigned*)(Yb + (long)e.x * HD);
        float v = __int_as_float(e.y);
        ax += v * bflo(y); ay += v * bfhi(y);
    }
    float nrm = norm[r];
    ((float2*)(out + r * HD))[lane] = make_float2(ax * nrm, ay * nrm);
}

// ---------- out = g * z + (1-g) * (x@Wh), g = sigmoid(x@Wt+b); z read from out ----------
__global__ __launch_bounds__(256) void k_final(const float* __restrict__ x,
                                               const short* __restrict__ WtT,
                                               const short* __restrict__ WhT,
                                               const float* __restrict__ bt,
                                               float* __restrict__ out) {
    __shared__ short lb[2 * HD * LDW];
    int tx = threadIdx.x;
    for (int i = tx; i < HD * 16; i += 256) {
        int n = i >> 4, kc = (i & 15) << 3;
        *(float4*)(&lb[n * LDW + kc])            = *(const float4*)(&WtT[n * HD + kc]);
        *(float4*)(&lb[HD * LDW + n * LDW + kc]) = *(const float4*)(&WhT[n * HD + kc]);
    }
    __syncthreads();

    int wv = tx >> 6, l = tx & 63;
    long row0 = (long)blockIdx.x * 64 + wv * 16;
    int mrow = l & 15, kg = l >> 4;
    const float* xp = x + (row0 + mrow) * HD + kg * 8;

    f32x4 at[8], ah[8];
    #pragma unroll
    for (int f = 0; f < 8; ++f) { at[f] = (f32x4){0.f,0.f,0.f,0.f}; ah[f] = (f32x4){0.f,0.f,0.f,0.f}; }

    #pragma unroll
    for (int c = 0; c < 4; ++c) {
        float4 a0 = *(const float4*)(xp + c * 32);
        float4 a1 = *(const float4*)(xp + c * 32 + 4);
        short8 a;
        a[0]=f2bf(a0.x); a[1]=f2bf(a0.y); a[2]=f2bf(a0.z); a[3]=f2bf(a0.w);
        a[4]=f2bf(a1.x); a[5]=f2bf(a1.y); a[6]=f2bf(a1.z); a[7]=f2bf(a1.w);
        #pragma unroll
        for (int f = 0; f < 8; ++f) {
            short8 b0 = *(short8*)(&lb[(16 * f + mrow) * LDW + c * 32 + kg * 8]);
            short8 b1 = *(short8*)(&lb[HD * LDW + (16 * f + mrow) * LDW + c * 32 + kg * 8]);
            at[f] = __builtin_amdgcn_mfma_f32_16x16x32_bf16(a, b0, at[f], 0, 0, 0);
            ah[f] = __builtin_amdgcn_mfma_f32_16x16x32_bf16(a, b1, ah[f], 0, 0, 0);
        }
    }
    #pragma unroll
    for (int f = 0; f < 8; ++f) {
        float bb = bt[16 * f + mrow];
        #pragma unroll
        for (int r = 0; r < 4; ++r) {
            long row = row0 + kg * 4 + r;
            long idx = row * HD + 16 * f + mrow;
            float z = out[idx];
            float g = 1.f / (1.f + __expf(-(at[f][r] + bb)));
            out[idx] = g * z + (1.f - g) * ah[f][r];
        }
    }
}

extern "C" void kernel_launch(void* const* d_in, const int* in_sizes, int n_in,
                              void* d_out, int out_size, void* d_ws, size_t ws_size,
                              hipStream_t stream) {
    const float* x     = (const float*)d_in[0];
    const float* adj   = (const float*)d_in[1];
    const int*   src   = (const int*)d_in[2];
    const int*   dst   = (const int*)d_in[3];
    const float* Wt    = (const float*)d_in[4];
    const float* bt    = (const float*)d_in[5];
    const float* Wh    = (const float*)d_in[6];
    const float* theta = (const float*)d_in[7];
    float* out = (float*)d_out;

    // workspace ~42.8 MB (same budget as proven R7)
    char* p = (char*)d_ws;
    float* norm   = (float*)p;  p += (size_t)NROW * 4;            // 320,000
    int*   total  = (int*)p;    p += (size_t)NROW * 4;            // 320,000
    int*   rowptr = (int*)p;    p += (size_t)NROW * 4;            // 320,000
    int*   bsum   = (int*)p;    p += 2048;
    int*   boffs  = (int*)p;    p += 2048;
    int*   tot_c  = (int*)p;    p += (size_t)NBT * 4;             // 5,120
    int*   cbase  = (int*)p;    p += (size_t)NBT * 4;             // 5,120
    int*   cc     = (int*)p;    p += (size_t)BATCH * KB * NBP * 4;// 327,680
    short* wbf    = (short*)p;  p += 3 * 16384 * 2;               // 98,304
    // RegionA (20.48 MB): bdeg (KB=64) -> epairA (after k_sum) -> Y (after k_refine)
    float* bdeg   = (float*)p;
    int2*  epairA = (int2*)p;
    short* Y      = (short*)p;  p += (size_t)NROW * HD * 2;       // 20,480,000
    // RegionB (21.12 MB): bcnt (KB=64, first 20.48 MB) -> epairB (after k_sum)
    int*   bcnt   = (int*)p;
    int2*  epairB = (int2*)p;   p += (size_t)(NEDG_TOT + NROW) * 8; // 21,120,000 (PADDED)

    k_hist  <<<BATCH * KB, 256, 0, stream>>>(adj, src, bdeg, bcnt, cc);
    k_sum   <<<SCAN_B, 256, 0, stream>>>(bcnt, bdeg, total, norm);
    k_scan1 <<<SCAN_B, 256, 0, stream>>>(total, rowptr, bsum);
    k_scan2 <<<1, 512, 0, stream>>>(bsum, boffs);
    k_fix   <<<SCAN_B, 256, 0, stream>>>(total, boffs, rowptr);
    k_coarse<<<1, 256, 0, stream>>>(cc, tot_c, cbase);
    k_scatA <<<BATCH * KB, 256, 0, stream>>>(adj, src, dst, norm, cc, epairA);  // epairA over dead bdeg
    k_refine<<<BATCH * NBUCK, 256, 0, stream>>>(cbase, tot_c, epairA, rowptr, epairB); // epairB over dead bcnt
    k_wcvt  <<<3 * 16384 / 256, 256, 0, stream>>>(theta, Wt, Wh, wbf);
    k_theta <<<NROW / 64, 256, 0, stream>>>(x, wbf, Y);           // Y over dead epairA
    k_gather<<<NROW / 4, 256, 0, stream>>>(rowptr, total, epairB, Y, norm, out);
    k_final <<<NROW / 64, 256, 0, stream>>>(x, wbf + 16384, wbf + 2 * 16384, bt, out);
}

// Round 10
// 182.085 us; speedup vs baseline: 1.2665x; 1.2665x over previous
//
#include <hip/hip_runtime.h>

#define BATCH 8
#define NNODE 10000
#define NEDGE 320000
#define HD    128
#define NROW  (BATCH * NNODE)       // 80000 rows
#define NEDG_TOT (BATCH * NEDGE)    // 2.56M edges
#define LDW 136                     // padded LDS row stride (bf16)
#define KB  32                      // hist/scatter blocks per batch
#define CEB (NEDGE / KB)            // 10000 edges per block
#define G   64                      // rows per coarse bucket
#define NBUCK 157                   // ceil(NNODE/G)
#define NBP 160                     // padded bucket stride
#define NBT (BATCH * NBP)           // 1280

typedef __attribute__((ext_vector_type(8))) short short8;
typedef __attribute__((ext_vector_type(4))) float f32x4;

__device__ __forceinline__ short f2bf(float f) {
    unsigned u = __float_as_uint(f);
    unsigned r = u + 0x7FFFu + ((u >> 16) & 1u);   // RNE
    return (short)(r >> 16);
}
__device__ __forceinline__ float bflo(unsigned y) { return __uint_as_float(y << 16); }
__device__ __forceinline__ float bfhi(unsigned y) { return __uint_as_float(y & 0xffff0000u); }

// ---------- pass 1: per-block LDS degree histogram + coarse bucket counts ----------
__global__ __launch_bounds__(256) void k_hist(const float* __restrict__ adj,
                                              const int* __restrict__ src,
                                              float* __restrict__ bdeg,
                                              int* __restrict__ cc) {
    __shared__ float sdeg[NNODE];   // 40 KB
    __shared__ int   scc[NBP];      // 640 B
    int t = threadIdx.x, blk = blockIdx.x;
    for (int i = t; i < NNODE; i += 256) sdeg[i] = 0.f;
    if (t < NBP) scc[t] = 0;
    __syncthreads();
    int b = blk >> 5, kb = blk & (KB - 1);
    long e0 = (long)b * NEDGE + (long)kb * CEB;
    for (int i = t; i < CEB; i += 256) {
        long e = e0 + i;
        int s = src[e];
        atomicAdd(&sdeg[s], adj[e]);
        atomicAdd(&scc[s >> 6], 1);
    }
    __syncthreads();
    float* bd = bdeg + (long)blk * NNODE;
    for (int i = t; i < NNODE; i += 256) bd[i] = sdeg[i];
    if (t < NBP) cc[blk * NBP + t] = scc[t];
}

// ---------- per-row norm from per-block degree partials ----------
__global__ __launch_bounds__(256) void k_norm(const float* __restrict__ bdeg,
                                              float* __restrict__ norm) {
    int r = blockIdx.x * 256 + threadIdx.x;
    if (r >= NROW) return;
    int b = r / NNODE, n = r % NNODE;
    const float* bd = bdeg + (long)b * KB * NNODE + n;
    float ds = 0.f;
    #pragma unroll
    for (int k = 0; k < KB; ++k) ds += bd[(long)k * NNODE];
    norm[r] = rsqrtf(ds + 1e-6f);
}

// ---------- coarse chain merged: totals + two scans (compact A, padded B) + bases ----------
__global__ __launch_bounds__(256) void k_coarse(int* __restrict__ cc,
                                                int* __restrict__ tot_c,
                                                int* __restrict__ cbaseA,
                                                int* __restrict__ cbaseB) {
    __shared__ int partA[256], partB[256];
    int t = threadIdx.x;
    int tot[5], locA[5], locB[5]; int runA = 0, runB = 0;
    #pragma unroll
    for (int j = 0; j < 5; ++j) {
        int gi = t * 5 + j, b = gi / NBP, bk = gi % NBP;
        int s = 0;
        for (int k = 0; k < KB; ++k) s += cc[(b * KB + k) * NBP + bk];
        tot[j] = s;
        locA[j] = runA; runA += s;
        locB[j] = runB; runB += (s + G + 1) & ~1;      // even upper bound for padded rows
    }
    partA[t] = runA; partB[t] = runB; __syncthreads();
    for (int off = 1; off < 256; off <<= 1) {
        int a = partA[t], bb = partB[t];
        int aa = (t >= off) ? partA[t - off] : 0;
        int ab = (t >= off) ? partB[t - off] : 0;
        __syncthreads();
        partA[t] = a + aa; partB[t] = bb + ab;
        __syncthreads();
    }
    int exA = (t == 0) ? 0 : partA[t - 1];
    int exB = (t == 0) ? 0 : partB[t - 1];
    #pragma unroll
    for (int j = 0; j < 5; ++j) {
        int gi = t * 5 + j, b = gi / NBP, bk = gi % NBP;
        tot_c[gi]  = tot[j];
        cbaseA[gi] = exA + locA[j];
        cbaseB[gi] = exB + locB[j];
        int run2 = exA + locA[j];
        for (int k = 0; k < KB; ++k) {
            int idx = (b * KB + k) * NBP + bk;
            int c = cc[idx];
            cc[idx] = run2;
            run2 += c;
        }
    }
}

// ---------- coarse scatter (64-row buckets), fold norm[dst] into value ----------
__global__ __launch_bounds__(256) void k_scatA(const float* __restrict__ adj,
                                               const int* __restrict__ src,
                                               const int* __restrict__ dst,
                                               const float* __restrict__ norm,
                                               const int* __restrict__ cbases,
                                               int2* __restrict__ epairA) {
    __shared__ int cur[NBP];
    int t = threadIdx.x, blk = blockIdx.x;
    if (t < NBP) cur[t] = cbases[blk * NBP + t];
    __syncthreads();
    int b = blk >> 5, kb = blk & (KB - 1);
    const float* nb = norm + b * NNODE;
    long e0 = (long)b * NEDGE + (long)kb * CEB;
    for (int i = t; i < CEB; i += 256) {
        long e = e0 + i;
        int s = src[e], d = dst[e];
        float v = adj[e] * nb[d];
        int p = atomicAdd(&cur[s >> 6], 1);
        epairA[p] = make_int2((s << 16) | d, __float_as_int(v));
    }
}

// ---------- refine: count rows, scan (padded even), emit rowptr/total + sorted edges ----------
__global__ __launch_bounds__(256) void k_refine(const int* __restrict__ cbaseA,
                                                const int* __restrict__ cbaseB,
                                                const int* __restrict__ tot_c,
                                                const int2* __restrict__ epairA,
                                                int* __restrict__ rowptr,
                                                int* __restrict__ total,
                                                int2* __restrict__ epairB) {
    __shared__ int rcnt[G];
    __shared__ int rcur[G];
    int t = threadIdx.x;
    int batch = blockIdx.x & 7, bk = blockIdx.x >> 3;
    if (t < G) rcnt[t] = 0;
    __syncthreads();
    int gi = batch * NBP + bk;
    int p0 = cbaseA[gi], n = tot_c[gi], pB = cbaseB[gi];
    // pass 1: count rows
    for (int i = t; i < n; i += 256)
        atomicAdd(&rcnt[(epairA[p0 + i].x >> 16) & (G - 1)], 1);
    __syncthreads();
    // wave-0 shfl scan of even-padded counts -> global row starts
    if (t < G) {
        int v = rcnt[t];
        int pv = (v + 1) & ~1;
        int inc = pv;
        #pragma unroll
        for (int off = 1; off < G; off <<= 1) {
            int u = __shfl_up(inc, off, G);
            if (t >= off) inc += u;
        }
        int start = pB + inc - pv;
        rcur[t] = start;
        int node = bk * G + t;
        if (node < NNODE) {
            long r = (long)batch * NNODE + node;
            rowptr[r] = start;
            total[r] = v;
        }
    }
    __syncthreads();
    // pass 2: place edges row-sorted (epairA window is L2-hot)
    for (int i = t; i < n; i += 256) {
        int2 e = epairA[p0 + i];
        int rl = (e.x >> 16) & (G - 1);
        int p = atomicAdd(&rcur[rl], 1);
        epairB[p] = make_int2(e.x & 0xffff, e.y);
    }
}

// ---------- weights -> bf16 transposed ----------
__global__ __launch_bounds__(256) void k_wcvt(const float* __restrict__ th,
                                              const float* __restrict__ Wt,
                                              const float* __restrict__ Wh,
                                              short* __restrict__ wbf) {
    int i = blockIdx.x * 256 + threadIdx.x;
    int w = i >> 14, idx = i & 16383;
    int n = idx >> 7, k = idx & 127;
    const float* W = (w == 0) ? th : ((w == 1) ? Wt : Wh);
    wbf[i] = f2bf(W[k * HD + n]);
}

// ---------- Y = bf16( x@theta )  (unnormalized; norms folded into edges / gather) ----------
__global__ __launch_bounds__(256) void k_theta(const float* __restrict__ x,
                                               const short* __restrict__ thT,
                                               short* __restrict__ Y) {
    __shared__ short lb[HD * LDW];
    int tx = threadIdx.x;
    for (int i = tx; i < HD * 16; i += 256) {
        int n = i >> 4, kc = (i & 15) << 3;
        *(float4*)(&lb[n * LDW + kc]) = *(const float4*)(&thT[n * HD + kc]);
    }
    __syncthreads();

    int wv = tx >> 6, l = tx & 63;
    long row0 = (long)blockIdx.x * 64 + wv * 16;
    int mrow = l & 15, kg = l >> 4;
    const float* xp = x + (row0 + mrow) * HD + kg * 8;

    f32x4 acc[8];
    #pragma unroll
    for (int f = 0; f < 8; ++f) acc[f] = (f32x4){0.f, 0.f, 0.f, 0.f};

    #pragma unroll
    for (int c = 0; c < 4; ++c) {
        float4 a0 = *(const float4*)(xp + c * 32);
        float4 a1 = *(const float4*)(xp + c * 32 + 4);
        short8 a;
        a[0]=f2bf(a0.x); a[1]=f2bf(a0.y); a[2]=f2bf(a0.z); a[3]=f2bf(a0.w);
        a[4]=f2bf(a1.x); a[5]=f2bf(a1.y); a[6]=f2bf(a1.z); a[7]=f2bf(a1.w);
        #pragma unroll
        for (int f = 0; f < 8; ++f) {
            short8 b = *(short8*)(&lb[(16 * f + mrow) * LDW + c * 32 + kg * 8]);
            acc[f] = __builtin_amdgcn_mfma_f32_16x16x32_bf16(a, b, acc[f], 0, 0, 0);
        }
    }
    #pragma unroll
    for (int f = 0; f < 8; ++f)
        #pragma unroll
        for (int r = 0; r < 4; ++r)
            Y[(row0 + kg * 4 + r) * HD + 16 * f + mrow] = f2bf(acc[f][r]);
}

// ---------- gather SpMM, XCD-swizzled (R7-proven) ----------
__global__ __launch_bounds__(256) void k_gather(const int* __restrict__ rowptr,
                                                const int* __restrict__ total,
                                                const int2* __restrict__ epair,
                                                const short* __restrict__ Y,
                                                const float* __restrict__ norm,
                                                float* __restrict__ out) {
    int batch = blockIdx.x & 7;
    int ib    = blockIdx.x >> 3;
    int wave = threadIdx.x >> 6, lane = threadIdx.x & 63;
    long r = (long)batch * NNODE + ib * 4 + wave;
    const short* Yb = Y + (long)batch * NNODE * HD + 2 * lane;
    int p0 = __builtin_amdgcn_readfirstlane(rowptr[r]);   // even -> 16B aligned
    int n  = __builtin_amdgcn_readfirstlane(total[r]);
    const int4* ep4 = (const int4*)(epair + p0);
    float ax = 0.f, ay = 0.f;
    int i = 0;
    for (; i + 8 <= n; i += 8) {
        int4 eA = ep4[(i >> 1) + 0];
        int4 eB = ep4[(i >> 1) + 1];
        int4 eC = ep4[(i >> 1) + 2];
        int4 eD = ep4[(i >> 1) + 3];
        unsigned y0 = *(const unsigned*)(Yb + (long)eA.x * HD);
        unsigned y1 = *(const unsigned*)(Yb + (long)eA.z * HD);
        unsigned y2 = *(const unsigned*)(Yb + (long)eB.x * HD);
        unsigned y3 = *(const unsigned*)(Yb + (long)eB.z * HD);
        unsigned y4 = *(const unsigned*)(Yb + (long)eC.x * HD);
        unsigned y5 = *(const unsigned*)(Yb + (long)eC.z * HD);
        unsigned y6 = *(const unsigned*)(Yb + (long)eD.x * HD);
        unsigned y7 = *(const unsigned*)(Yb + (long)eD.z * HD);
        float v0 = __int_as_float(eA.y), v1 = __int_as_float(eA.w);
        float v2 = __int_as_float(eB.y), v3 = __int_as_float(eB.w);
        float v4 = __int_as_float(eC.y), v5 = __int_as_float(eC.w);
        float v6 = __int_as_float(eD.y), v7 = __int_as_float(eD.w);
        ax += v0 * bflo(y0); ay += v0 * bfhi(y0);
        ax += v1 * bflo(y1); ay += v1 * bfhi(y1);
        ax += v2 * bflo(y2); ay += v2 * bfhi(y2);
        ax += v3 * bflo(y3); ay += v3 * bfhi(y3);
        ax += v4 * bflo(y4); ay += v4 * bfhi(y4);
        ax += v5 * bflo(y5); ay += v5 * bfhi(y5);
        ax += v6 * bflo(y6); ay += v6 * bfhi(y6);
        ax += v7 * bflo(y7); ay += v7 * bfhi(y7);
    }
    for (; i + 2 <= n; i += 2) {
        int4 eA = ep4[i >> 1];
        unsigned y0 = *(const unsigned*)(Yb + (long)eA.x * HD);
        unsigned y1 = *(const unsigned*)(Yb + (long)eA.z * HD);
        float v0 = __int_as_float(eA.y), v1 = __int_as_float(eA.w);
        ax += v0 * bflo(y0); ay += v0 * bfhi(y0);
        ax += v1 * bflo(y1); ay += v1 * bfhi(y1);
    }
    if (i < n) {
        int2 e = epair[p0 + i];
        unsigned y = *(const unsigned*)(Yb + (long)e.x * HD);
        float v = __int_as_float(e.y);
        ax += v * bflo(y); ay += v * bfhi(y);
    }
    float nrm = norm[r];
    ((float2*)(out + r * HD))[lane] = make_float2(ax * nrm, ay * nrm);
}

// ---------- out = g * z + (1-g) * (x@Wh), g = sigmoid(x@Wt+b); z read from out ----------
__global__ __launch_bounds__(256) void k_final(const float* __restrict__ x,
                                               const short* __restrict__ WtT,
                                               const short* __restrict__ WhT,
                                               const float* __restrict__ bt,
                                               float* __restrict__ out) {
    __shared__ short lb[2 * HD * LDW];
    int tx = threadIdx.x;
    for (int i = tx; i < HD * 16; i += 256) {
        int n = i >> 4, kc = (i & 15) << 3;
        *(float4*)(&lb[n * LDW + kc])            = *(const float4*)(&WtT[n * HD + kc]);
        *(float4*)(&lb[HD * LDW + n * LDW + kc]) = *(const float4*)(&WhT[n * HD + kc]);
    }
    __syncthreads();

    int wv = tx >> 6, l = tx & 63;
    long row0 = (long)blockIdx.x * 64 + wv * 16;
    int mrow = l & 15, kg = l >> 4;
    const float* xp = x + (row0 + mrow) * HD + kg * 8;

    f32x4 at[8], ah[8];
    #pragma unroll
    for (int f = 0; f < 8; ++f) { at[f] = (f32x4){0.f,0.f,0.f,0.f}; ah[f] = (f32x4){0.f,0.f,0.f,0.f}; }

    #pragma unroll
    for (int c = 0; c < 4; ++c) {
        float4 a0 = *(const float4*)(xp + c * 32);
        float4 a1 = *(const float4*)(xp + c * 32 + 4);
        short8 a;
        a[0]=f2bf(a0.x); a[1]=f2bf(a0.y); a[2]=f2bf(a0.z); a[3]=f2bf(a0.w);
        a[4]=f2bf(a1.x); a[5]=f2bf(a1.y); a[6]=f2bf(a1.z); a[7]=f2bf(a1.w);
        #pragma unroll
        for (int f = 0; f < 8; ++f) {
            short8 b0 = *(short8*)(&lb[(16 * f + mrow) * LDW + c * 32 + kg * 8]);
            short8 b1 = *(short8*)(&lb[HD * LDW + (16 * f + mrow) * LDW + c * 32 + kg * 8]);
            at[f] = __builtin_amdgcn_mfma_f32_16x16x32_bf16(a, b0, at[f], 0, 0, 0);
            ah[f] = __builtin_amdgcn_mfma_f32_16x16x32_bf16(a, b1, ah[f], 0, 0, 0);
        }
    }
    #pragma unroll
    for (int f = 0; f < 8; ++f) {
        float bb = bt[16 * f + mrow];
        #pragma unroll
        for (int r = 0; r < 4; ++r) {
            long row = row0 + kg * 4 + r;
            long idx = row * HD + 16 * f + mrow;
            float z = out[idx];
            float g = 1.f / (1.f + __expf(-(at[f][r] + bb)));
            out[idx] = g * z + (1.f - g) * ah[f][r];
        }
    }
}

extern "C" void kernel_launch(void* const* d_in, const int* in_sizes, int n_in,
                              void* d_out, int out_size, void* d_ws, size_t ws_size,
                              hipStream_t stream) {
    const float* x     = (const float*)d_in[0];
    const float* adj   = (const float*)d_in[1];
    const int*   src   = (const int*)d_in[2];
    const int*   dst   = (const int*)d_in[3];
    const float* Wt    = (const float*)d_in[4];
    const float* bt    = (const float*)d_in[5];
    const float* Wh    = (const float*)d_in[6];
    const float* theta = (const float*)d_in[7];
    float* out = (float*)d_out;

    // workspace ~42.87 MB
    char* p = (char*)d_ws;
    float* norm   = (float*)p;  p += (size_t)NROW * 4;              // 320,000
    int*   total  = (int*)p;    p += (size_t)NROW * 4;              // 320,000
    int*   rowptr = (int*)p;    p += (size_t)NROW * 4;              // 320,000
    int*   tot_c  = (int*)p;    p += (size_t)NBT * 4;               // 5,120
    int*   cbaseA = (int*)p;    p += (size_t)NBT * 4;               // 5,120
    int*   cbaseB = (int*)p;    p += (size_t)NBT * 4;               // 5,120
    int*   cc     = (int*)p;    p += (size_t)BATCH * KB * NBP * 4;  // 163,840
    short* wbf    = (short*)p;  p += 3 * 16384 * 2;                 // 98,304
    // RegionA (20.48 MB): bdeg (KB=32, 10.24M) -> epairA (20.48M) -> Y (20.48M)
    float* bdeg   = (float*)p;
    int2*  epairA = (int2*)p;
    short* Y      = (short*)p;  p += (size_t)NROW * HD * 2;         // 20,480,000
    // RegionB: epairB padded (compact + per-bucket even padding bound)
    int2*  epairB = (int2*)p;   p += (size_t)(NEDG_TOT + NBT * 66) * 8; // 21,155,840

    k_hist  <<<BATCH * KB, 256, 0, stream>>>(adj, src, bdeg, cc);
    k_norm  <<<(NROW + 255) / 256, 256, 0, stream>>>(bdeg, norm);
    k_coarse<<<1, 256, 0, stream>>>(cc, tot_c, cbaseA, cbaseB);
    k_scatA <<<BATCH * KB, 256, 0, stream>>>(adj, src, dst, norm, cc, epairA); // over dead bdeg
    k_refine<<<BATCH * NBUCK, 256, 0, stream>>>(cbaseA, cbaseB, tot_c, epairA, rowptr, total, epairB);
    k_wcvt  <<<3 * 16384 / 256, 256, 0, stream>>>(theta, Wt, Wh, wbf);
    k_theta <<<NROW / 64, 256, 0, stream>>>(x, wbf, Y);             // Y over dead epairA
    k_gather<<<NROW / 4, 256, 0, stream>>>(rowptr, total, epairB, Y, norm, out);
    k_final <<<NROW / 64, 256, 0, stream>>>(x, wbf + 16384, wbf + 2 * 16384, bt, out);
}

// Round 11
// 171.363 us; speedup vs baseline: 1.3457x; 1.0626x over previous
//
#include <hip/hip_runtime.h>

#define BATCH 8
#define NNODE 10000
#define NEDGE 320000
#define HD    128
#define NROW  (BATCH * NNODE)       // 80000 rows
#define NEDG_TOT (BATCH * NEDGE)    // 2.56M edges
#define SCAN_B ((NROW + 255) / 256) // 313
#define LDW 136                     // padded LDS row stride (bf16)
#define KB  32                      // hist/scatter blocks per batch
#define CEB (NEDGE / KB)            // 10000 edges per block
#define G   64                      // rows per coarse bucket
#define NBUCK 157                   // ceil(NNODE/G)
#define NBP 160                     // padded bucket stride
#define NBT (BATCH * NBP)           // 1280
#define WCVT_B 192                  // 3*16384/256

typedef __attribute__((ext_vector_type(8))) short short8;
typedef __attribute__((ext_vector_type(4))) float f32x4;

__device__ __forceinline__ short f2bf(float f) {
    unsigned u = __float_as_uint(f);
    unsigned r = u + 0x7FFFu + ((u >> 16) & 1u);   // RNE
    return (short)(r >> 16);
}
__device__ __forceinline__ float bflo(unsigned y) { return __uint_as_float(y << 16); }
__device__ __forceinline__ float bfhi(unsigned y) { return __uint_as_float(y & 0xffff0000u); }

// ---------- pass 1: per-block LDS degree histogram + coarse bucket counts ----------
__global__ __launch_bounds__(256) void k_hist(const float* __restrict__ adj,
                                              const int* __restrict__ src,
                                              float* __restrict__ bdeg,
                                              int* __restrict__ cc) {
    __shared__ float sdeg[NNODE];   // 40 KB
    __shared__ int   scc[NBP];      // 640 B
    int t = threadIdx.x, blk = blockIdx.x;
    for (int i = t; i < NNODE; i += 256) sdeg[i] = 0.f;
    if (t < NBP) scc[t] = 0;
    __syncthreads();
    int b = blk >> 5, kb = blk & (KB - 1);
    long e0 = (long)b * NEDGE + (long)kb * CEB;
    for (int i = t; i < CEB; i += 256) {
        long e = e0 + i;
        int s = src[e];
        atomicAdd(&sdeg[s], adj[e]);
        atomicAdd(&scc[s >> 6], 1);
    }
    __syncthreads();
    float* bd = bdeg + (long)blk * NNODE;
    for (int i = t; i < NNODE; i += 256) bd[i] = sdeg[i];
    if (t < NBP) cc[blk * NBP + t] = scc[t];
}

// ---------- fused: norm (blocks 0..312) | wcvt (313..504) | coarse chain (505) ----------
__global__ __launch_bounds__(256) void k_misc(const float* __restrict__ bdeg,
                                              float* __restrict__ norm,
                                              const float* __restrict__ th,
                                              const float* __restrict__ Wt,
                                              const float* __restrict__ Wh,
                                              short* __restrict__ wbf,
                                              int* __restrict__ cc,
                                              int* __restrict__ tot_c,
                                              int* __restrict__ cbaseA,
                                              int* __restrict__ cbaseB) {
    __shared__ int partA[256], partB[256];
    int t = threadIdx.x, blk = blockIdx.x;
    if (blk < SCAN_B) {
        // per-row norm from per-block degree partials
        int r = blk * 256 + t;
        if (r >= NROW) return;
        int b = r / NNODE, n = r % NNODE;
        const float* bd = bdeg + (long)b * KB * NNODE + n;
        float ds = 0.f;
        #pragma unroll
        for (int k = 0; k < KB; ++k) ds += bd[(long)k * NNODE];
        norm[r] = rsqrtf(ds + 1e-6f);
    } else if (blk < SCAN_B + WCVT_B) {
        // weights -> bf16 transposed
        int i = (blk - SCAN_B) * 256 + t;
        int w = i >> 14, idx = i & 16383;
        int n = idx >> 7, k = idx & 127;
        const float* W = (w == 0) ? th : ((w == 1) ? Wt : Wh);
        wbf[i] = f2bf(W[k * HD + n]);
    } else {
        // coarse chain: bucket totals + compact scan (A) + padded scan (B) + block bases
        int tot[5], locA[5], locB[5]; int runA = 0, runB = 0;
        #pragma unroll
        for (int j = 0; j < 5; ++j) {
            int gi = t * 5 + j, b = gi / NBP, bk = gi % NBP;
            int s = 0;
            for (int k = 0; k < KB; ++k) s += cc[(b * KB + k) * NBP + bk];
            tot[j] = s;
            locA[j] = runA; runA += s;
            locB[j] = runB; runB += (s + 3 * G + 3) & ~3;   // 4-aligned padded bound
        }
        partA[t] = runA; partB[t] = runB; __syncthreads();
        for (int off = 1; off < 256; off <<= 1) {
            int a = partA[t], bb = partB[t];
            int aa = (t >= off) ? partA[t - off] : 0;
            int ab = (t >= off) ? partB[t - off] : 0;
            __syncthreads();
            partA[t] = a + aa; partB[t] = bb + ab;
            __syncthreads();
        }
        int exA = (t == 0) ? 0 : partA[t - 1];
        int exB = (t == 0) ? 0 : partB[t - 1];
        #pragma unroll
        for (int j = 0; j < 5; ++j) {
            int gi = t * 5 + j, b = gi / NBP, bk = gi % NBP;
            tot_c[gi]  = tot[j];
            cbaseA[gi] = exA + locA[j];
            cbaseB[gi] = exB + locB[j];
            int run2 = exA + locA[j];
            for (int k = 0; k < KB; ++k) {
                int idx = (b * KB + k) * NBP + bk;
                int c = cc[idx];
                cc[idx] = run2;
                run2 += c;
            }
        }
    }
}

// ---------- coarse scatter (64-row buckets), fold norm[dst] into value ----------
__global__ __launch_bounds__(256) void k_scatA(const float* __restrict__ adj,
                                               const int* __restrict__ src,
                                               const int* __restrict__ dst,
                                               const float* __restrict__ norm,
                                               const int* __restrict__ cbases,
                                               int2* __restrict__ epairA) {
    __shared__ int cur[NBP];
    int t = threadIdx.x, blk = blockIdx.x;
    if (t < NBP) cur[t] = cbases[blk * NBP + t];
    __syncthreads();
    int b = blk >> 5, kb = blk & (KB - 1);
    const float* nb = norm + b * NNODE;
    long e0 = (long)b * NEDGE + (long)kb * CEB;
    for (int i = t; i < CEB; i += 256) {
        long e = e0 + i;
        int s = src[e], d = dst[e];
        float v = adj[e] * nb[d];
        int p = atomicAdd(&cur[s >> 6], 1);
        epairA[p] = make_int2((s << 16) | d, __float_as_int(v));
    }
}

// ---------- refine: count rows, 4-padded scan -> rowptr/total, emit packed 4B edges ----------
__global__ __launch_bounds__(256) void k_refine(const int* __restrict__ cbaseA,
                                                const int* __restrict__ cbaseB,
                                                const int* __restrict__ tot_c,
                                                const int2* __restrict__ epairA,
                                                int* __restrict__ rowptr,
                                                int* __restrict__ total,
                                                int* __restrict__ epakB) {
    __shared__ int rcnt[G];
    __shared__ int rcur[G];
    int t = threadIdx.x;
    int batch = blockIdx.x & 7, bk = blockIdx.x >> 3;
    if (t < G) rcnt[t] = 0;
    __syncthreads();
    int gi = batch * NBP + bk;
    int p0 = cbaseA[gi], n = tot_c[gi], pB = cbaseB[gi];
    // pass 1: count rows
    for (int i = t; i < n; i += 256)
        atomicAdd(&rcnt[(epairA[p0 + i].x >> 16) & (G - 1)], 1);
    __syncthreads();
    // wave-0 shfl scan of 4-padded counts -> global row starts (4-aligned)
    if (t < G) {
        int v = rcnt[t];
        int pv = (v + 3) & ~3;
        int inc = pv;
        #pragma unroll
        for (int off = 1; off < G; off <<= 1) {
            int u = __shfl_up(inc, off, G);
            if (t >= off) inc += u;
        }
        int start = pB + inc - pv;
        rcur[t] = start;
        int node = bk * G + t;
        if (node < NNODE) {
            long r = (long)batch * NNODE + node;
            rowptr[r] = start;
            total[r] = v;
        }
    }
    __syncthreads();
    // pass 2: place packed edges (d | bf16(v)<<16) row-sorted
    for (int i = t; i < n; i += 256) {
        int2 e = epairA[p0 + i];
        int rl = (e.x >> 16) & (G - 1);
        int p = atomicAdd(&rcur[rl], 1);
        unsigned vbf = (unsigned short)f2bf(__int_as_float(e.y));
        epakB[p] = (e.x & 0xffff) | (vbf << 16);
    }
}

// ---------- Y = bf16( x@theta )  (unnormalized) ----------
__global__ __launch_bounds__(256) void k_theta(const float* __restrict__ x,
                                               const short* __restrict__ thT,
                                               short* __restrict__ Y) {
    __shared__ short lb[HD * LDW];
    int tx = threadIdx.x;
    for (int i = tx; i < HD * 16; i += 256) {
        int n = i >> 4, kc = (i & 15) << 3;
        *(float4*)(&lb[n * LDW + kc]) = *(const float4*)(&thT[n * HD + kc]);
    }
    __syncthreads();

    int wv = tx >> 6, l = tx & 63;
    long row0 = (long)blockIdx.x * 64 + wv * 16;
    int mrow = l & 15, kg = l >> 4;
    const float* xp = x + (row0 + mrow) * HD + kg * 8;

    f32x4 acc[8];
    #pragma unroll
    for (int f = 0; f < 8; ++f) acc[f] = (f32x4){0.f, 0.f, 0.f, 0.f};

    #pragma unroll
    for (int c = 0; c < 4; ++c) {
        float4 a0 = *(const float4*)(xp + c * 32);
        float4 a1 = *(const float4*)(xp + c * 32 + 4);
        short8 a;
        a[0]=f2bf(a0.x); a[1]=f2bf(a0.y); a[2]=f2bf(a0.z); a[3]=f2bf(a0.w);
        a[4]=f2bf(a1.x); a[5]=f2bf(a1.y); a[6]=f2bf(a1.z); a[7]=f2bf(a1.w);
        #pragma unroll
        for (int f = 0; f < 8; ++f) {
            short8 b = *(short8*)(&lb[(16 * f + mrow) * LDW + c * 32 + kg * 8]);
            acc[f] = __builtin_amdgcn_mfma_f32_16x16x32_bf16(a, b, acc[f], 0, 0, 0);
        }
    }
    #pragma unroll
    for (int f = 0; f < 8; ++f)
        #pragma unroll
        for (int r = 0; r < 4; ++r)
            Y[(row0 + kg * 4 + r) * HD + 16 * f + mrow] = f2bf(acc[f][r]);
}

// ---------- gather SpMM: packed 4B edges, 16-edge unroll, XCD-swizzled ----------
__global__ __launch_bounds__(256) void k_gather(const int* __restrict__ rowptr,
                                                const int* __restrict__ total,
                                                const int* __restrict__ epak,
                                                const short* __restrict__ Y,
                                                const float* __restrict__ norm,
                                                float* __restrict__ out) {
    int batch = blockIdx.x & 7;
    int ib    = blockIdx.x >> 3;
    int wave = threadIdx.x >> 6, lane = threadIdx.x & 63;
    long r = (long)batch * NNODE + ib * 4 + wave;
    const short* Yb = Y + (long)batch * NNODE * HD + 2 * lane;
    int p0 = __builtin_amdgcn_readfirstlane(rowptr[r]);   // multiple of 4 -> 16B aligned
    int n  = __builtin_amdgcn_readfirstlane(total[r]);
    const int* ep = epak + p0;
    float ax = 0.f, ay = 0.f;
    int i = 0;
    for (; i + 16 <= n; i += 16) {
        int4 mA = *(const int4*)(ep + i);
        int4 mB = *(const int4*)(ep + i + 4);
        int4 mC = *(const int4*)(ep + i + 8);
        int4 mD = *(const int4*)(ep + i + 12);
        unsigned y0 = *(const unsigned*)(Yb + (long)(mA.x & 0xffff) * HD);
        unsigned y1 = *(const unsigned*)(Yb + (long)(mA.y & 0xffff) * HD);
        unsigned y2 = *(const unsigned*)(Yb + (long)(mA.z & 0xffff) * HD);
        unsigned y3 = *(const unsigned*)(Yb + (long)(mA.w & 0xffff) * HD);
        unsigned y4 = *(const unsigned*)(Yb + (long)(mB.x & 0xffff) * HD);
        unsigned y5 = *(const unsigned*)(Yb + (long)(mB.y & 0xffff) * HD);
        unsigned y6 = *(const unsigned*)(Yb + (long)(mB.z & 0xffff) * HD);
        unsigned y7 = *(const unsigned*)(Yb + (long)(mB.w & 0xffff) * HD);
        unsigned y8 = *(const unsigned*)(Yb + (long)(mC.x & 0xffff) * HD);
        unsigned y9 = *(const unsigned*)(Yb + (long)(mC.y & 0xffff) * HD);
        unsigned yA = *(const unsigned*)(Yb + (long)(mC.z & 0xffff) * HD);
        unsigned yB = *(const unsigned*)(Yb + (long)(mC.w & 0xffff) * HD);
        unsigned yC = *(const unsigned*)(Yb + (long)(mD.x & 0xffff) * HD);
        unsigned yD = *(const unsigned*)(Yb + (long)(mD.y & 0xffff) * HD);
        unsigned yE = *(const unsigned*)(Yb + (long)(mD.z & 0xffff) * HD);
        unsigned yF = *(const unsigned*)(Yb + (long)(mD.w & 0xffff) * HD);
        float v0 = bfhi((unsigned)mA.x), v1 = bfhi((unsigned)mA.y);
        float v2 = bfhi((unsigned)mA.z), v3 = bfhi((unsigned)mA.w);
        float v4 = bfhi((unsigned)mB.x), v5 = bfhi((unsigned)mB.y);
        float v6 = bfhi((unsigned)mB.z), v7 = bfhi((unsigned)mB.w);
        float v8 = bfhi((unsigned)mC.x), v9 = bfhi((unsigned)mC.y);
        float vA = bfhi((unsigned)mC.z), vB = bfhi((unsigned)mC.w);
        float vC = bfhi((unsigned)mD.x), vD = bfhi((unsigned)mD.y);
        float vE = bfhi((unsigned)mD.z), vF = bfhi((unsigned)mD.w);
        ax += v0 * bflo(y0); ay += v0 * bfhi(y0);
        ax += v1 * bflo(y1); ay += v1 * bfhi(y1);
        ax += v2 * bflo(y2); ay += v2 * bfhi(y2);
        ax += v3 * bflo(y3); ay += v3 * bfhi(y3);
        ax += v4 * bflo(y4); ay += v4 * bfhi(y4);
        ax += v5 * bflo(y5); ay += v5 * bfhi(y5);
        ax += v6 * bflo(y6); ay += v6 * bfhi(y6);
        ax += v7 * bflo(y7); ay += v7 * bfhi(y7);
        ax += v8 * bflo(y8); ay += v8 * bfhi(y8);
        ax += v9 * bflo(y9); ay += v9 * bfhi(y9);
        ax += vA * bflo(yA); ay += vA * bfhi(yA);
        ax += vB * bflo(yB); ay += vB * bfhi(yB);
        ax += vC * bflo(yC); ay += vC * bfhi(yC);
        ax += vD * bflo(yD); ay += vD * bfhi(yD);
        ax += vE * bflo(yE); ay += vE * bfhi(yE);
        ax += vF * bflo(yF); ay += vF * bfhi(yF);
    }
    for (; i + 4 <= n; i += 4) {
        int4 mA = *(const int4*)(ep + i);
        unsigned y0 = *(const unsigned*)(Yb + (long)(mA.x & 0xffff) * HD);
        unsigned y1 = *(const unsigned*)(Yb + (long)(mA.y & 0xffff) * HD);
        unsigned y2 = *(const unsigned*)(Yb + (long)(mA.z & 0xffff) * HD);
        unsigned y3 = *(const unsigned*)(Yb + (long)(mA.w & 0xffff) * HD);
        float v0 = bfhi((unsigned)mA.x), v1 = bfhi((unsigned)mA.y);
        float v2 = bfhi((unsigned)mA.z), v3 = bfhi((unsigned)mA.w);
        ax += v0 * bflo(y0); ay += v0 * bfhi(y0);
        ax += v1 * bflo(y1); ay += v1 * bfhi(y1);
        ax += v2 * bflo(y2); ay += v2 * bfhi(y2);
        ax += v3 * bflo(y3); ay += v3 * bfhi(y3);
    }
    for (; i < n; ++i) {
        unsigned e = (unsigned)ep[i];
        unsigned y = *(const unsigned*)(Yb + (long)(e & 0xffff) * HD);
        float v = bfhi(e);
        ax += v * bflo(y); ay += v * bfhi(y);
    }
    float nrm = norm[r];
    ((float2*)(out + r * HD))[lane] = make_float2(ax * nrm, ay * nrm);
}

// ---------- out = g * z + (1-g) * (x@Wh), g = sigmoid(x@Wt+b); z read from out ----------
__global__ __launch_bounds__(256) void k_final(const float* __restrict__ x,
                                               const short* __restrict__ WtT,
                                               const short* __restrict__ WhT,
                                               const float* __restrict__ bt,
                                               float* __restrict__ out) {
    __shared__ short lb[2 * HD * LDW];
    int tx = threadIdx.x;
    for (int i = tx; i < HD * 16; i += 256) {
        int n = i >> 4, kc = (i & 15) << 3;
        *(float4*)(&lb[n * LDW + kc])            = *(const float4*)(&WtT[n * HD + kc]);
        *(float4*)(&lb[HD * LDW + n * LDW + kc]) = *(const float4*)(&WhT[n * HD + kc]);
    }
    __syncthreads();

    int wv = tx >> 6, l = tx & 63;
    long row0 = (long)blockIdx.x * 64 + wv * 16;
    int mrow = l & 15, kg = l >> 4;
    const float* xp = x + (row0 + mrow) * HD + kg * 8;

    f32x4 at[8], ah[8];
    #pragma unroll
    for (int f = 0; f < 8; ++f) { at[f] = (f32x4){0.f,0.f,0.f,0.f}; ah[f] = (f32x4){0.f,0.f,0.f,0.f}; }

    #pragma unroll
    for (int c = 0; c < 4; ++c) {
        float4 a0 = *(const float4*)(xp + c * 32);
        float4 a1 = *(const float4*)(xp + c * 32 + 4);
        short8 a;
        a[0]=f2bf(a0.x); a[1]=f2bf(a0.y); a[2]=f2bf(a0.z); a[3]=f2bf(a0.w);
        a[4]=f2bf(a1.x); a[5]=f2bf(a1.y); a[6]=f2bf(a1.z); a[7]=f2bf(a1.w);
        #pragma unroll
        for (int f = 0; f < 8; ++f) {
            short8 b0 = *(short8*)(&lb[(16 * f + mrow) * LDW + c * 32 + kg * 8]);
            short8 b1 = *(short8*)(&lb[HD * LDW + (16 * f + mrow) * LDW + c * 32 + kg * 8]);
            at[f] = __builtin_amdgcn_mfma_f32_16x16x32_bf16(a, b0, at[f], 0, 0, 0);
            ah[f] = __builtin_amdgcn_mfma_f32_16x16x32_bf16(a, b1, ah[f], 0, 0, 0);
        }
    }
    #pragma unroll
    for (int f = 0; f < 8; ++f) {
        float bb = bt[16 * f + mrow];
        #pragma unroll
        for (int r = 0; r < 4; ++r) {
            long row = row0 + kg * 4 + r;
            long idx = row * HD + 16 * f + mrow;
            float z = out[idx];
            float g = 1.f / (1.f + __expf(-(at[f][r] + bb)));
            out[idx] = g * z + (1.f - g) * ah[f][r];
        }
    }
}

extern "C" void kernel_launch(void* const* d_in, const int* in_sizes, int n_in,
                              void* d_out, int out_size, void* d_ws, size_t ws_size,
                              hipStream_t stream) {
    const float* x     = (const float*)d_in[0];
    const float* adj   = (const float*)d_in[1];
    const int*   src   = (const int*)d_in[2];
    const int*   dst   = (const int*)d_in[3];
    const float* Wt    = (const float*)d_in[4];
    const float* bt    = (const float*)d_in[5];
    const float* Wh    = (const float*)d_in[6];
    const float* theta = (const float*)d_in[7];
    float* out = (float*)d_out;

    // workspace ~33.3 MB
    char* p = (char*)d_ws;
    float* norm   = (float*)p;  p += (size_t)NROW * 4;              // 320,000
    int*   total  = (int*)p;    p += (size_t)NROW * 4;              // 320,000
    int*   rowptr = (int*)p;    p += (size_t)NROW * 4;              // 320,000
    int*   tot_c  = (int*)p;    p += (size_t)NBT * 4;               // 5,120
    int*   cbaseA = (int*)p;    p += (size_t)NBT * 4;               // 5,120
    int*   cbaseB = (int*)p;    p += (size_t)NBT * 4;               // 5,120
    int*   cc     = (int*)p;    p += (size_t)BATCH * KB * NBP * 4;  // 163,840
    short* wbf    = (short*)p;  p += 3 * 16384 * 2;                 // 98,304
    // RegionA (20.48 MB): bdeg (10.24M) -> epairA (20.48M) -> Y (20.48M)
    float* bdeg   = (float*)p;
    int2*  epairA = (int2*)p;
    short* Y      = (short*)p;  p += (size_t)NROW * HD * 2;         // 20,480,000
    // RegionB: packed 4B edges, 4-padded rows (bound: n + 3G+3 per bucket, 4-aligned)
    int*   epakB  = (int*)p;    p += (size_t)(NEDG_TOT + NBT * 256) * 4; // 11,551,232

    k_hist  <<<BATCH * KB, 256, 0, stream>>>(adj, src, bdeg, cc);
    k_misc  <<<SCAN_B + WCVT_B + 1, 256, 0, stream>>>(bdeg, norm, theta, Wt, Wh, wbf,
                                                      cc, tot_c, cbaseA, cbaseB);
    k_scatA <<<BATCH * KB, 256, 0, stream>>>(adj, src, dst, norm, cc, epairA); // over dead bdeg
    k_refine<<<BATCH * NBUCK, 256, 0, stream>>>(cbaseA, cbaseB, tot_c, epairA, rowptr, total, epakB);
    k_theta <<<NROW / 64, 256, 0, stream>>>(x, wbf, Y);             // Y over dead epairA
    k_gather<<<NROW / 4, 256, 0, stream>>>(rowptr, total, epakB, Y, norm, out);
    k_final <<<NROW / 64, 256, 0, stream>>>(x, wbf + 16384, wbf + 2 * 16384, bt, out);
}